// Round 1
// baseline (498.226 us; speedup 1.0000x reference)
//
#include <hip/hip_runtime.h>
#include <cstdint>

// FracAttention: B=2, S=2048, D_MODEL=2048, H=16, DK=128
#define S_LEN   2048
#define DMODEL  2048
#define NHEADS  16
#define DK      128
#define MROWS   4096   // B*S

typedef _Float16 f16;
using f16x8 = __attribute__((ext_vector_type(8))) _Float16;
using f16x4 = __attribute__((ext_vector_type(4))) _Float16;
using f32x4 = __attribute__((ext_vector_type(4))) float;

typedef const __attribute__((address_space(1))) unsigned int gu32;
typedef __attribute__((address_space(3))) unsigned int lu32;

__device__ __forceinline__ void gl2lds16(const void* g, void* l) {
    // async global->LDS, 16 B per lane; LDS dest = wave-uniform base + lane*16
    __builtin_amdgcn_global_load_lds((gu32*)g, (lu32*)l, 16, 0, 0);
}

// ---------------------------------------------------------------------------
// fp32 -> fp16 convert, all 7 tensors, grid-stride (G11: cap blocks, stride).
// ---------------------------------------------------------------------------
#define CVT_BLOCKS 2048
__global__ __launch_bounds__(256) void cvt_all(
    const float* __restrict__ q, const float* __restrict__ k,
    const float* __restrict__ v, const float* __restrict__ wq,
    const float* __restrict__ wk, const float* __restrict__ wv,
    const float* __restrict__ wo,
    f16* cq, f16* ck, f16* cv, f16* cwq, f16* cwk, f16* cwv, f16* cwo)
{
    const unsigned QS = 2097152u;   // float4 count of q/k/v (8,388,608 elems)
    const unsigned WS = 1048576u;   // float4 count of each weight
    const unsigned total = 3u * QS + 4u * WS;   // 10,485,760
    unsigned i = blockIdx.x * 256 + threadIdx.x;
    const unsigned stride = CVT_BLOCKS * 256;
    for (; i < total; i += stride) {
        const float* src; f16* dst; unsigned off;
        if      (i < QS)              { src = q;  dst = cq;  off = i; }
        else if (i < 2u*QS)           { src = k;  dst = ck;  off = i - QS; }
        else if (i < 3u*QS)           { src = v;  dst = cv;  off = i - 2u*QS; }
        else if (i < 3u*QS + WS)      { src = wq; dst = cwq; off = i - 3u*QS; }
        else if (i < 3u*QS + 2u*WS)   { src = wk; dst = cwk; off = i - (3u*QS + WS); }
        else if (i < 3u*QS + 3u*WS)   { src = wv; dst = cwv; off = i - (3u*QS + 2u*WS); }
        else                          { src = wo; dst = cwo; off = i - (3u*QS + 3u*WS); }
        float4 x = ((const float4*)src)[off];
        f16x4 o; o[0] = (f16)x.x; o[1] = (f16)x.y; o[2] = (f16)x.z; o[3] = (f16)x.w;
        ((f16x4*)dst)[off] = o;
    }
}

// ---------------------------------------------------------------------------
// fp16 MFMA GEMM core v2: C[M][N] = A[M][K] @ W[N][K]^T + bias
// BM=128 x BN=256, BK=32, 512 threads = 8 waves (2 wave-rows x 4 wave-cols),
// per-wave 64x64 output (4x4 16x16x32 frags).
// 3-stage LDS pipeline: compute tile t from buf t%3 while tile t+2 streams
// into buf (t+2)%3 via global_load_lds; ONE counted s_waitcnt vmcnt(3) per
// K-tile (vmcnt(0) only at the final tile) -- loads stay in flight across
// barriers (T3+T4). ds_read bank conflicts removed with an XOR swizzle
// (T2): global source k-chunk pre-swizzled by (row>>1)&3, ds_read applies
// the same involution; LDS dest of global_load_lds stays linear (m104).
// setprio(1) wraps each MFMA cluster (T5).
// mode 0: fp32 out [M][N]
// mode 1: f16 out head-permuted [B,H,S,DK]             (K)
// mode 2: f16 out head-permuted + transposed [B,H,DK,S] (V -> VT)
// mode 3: f16 out head-permuted, scaled by sa[h]/max(sb[h],1) (Q)
// ---------------------------------------------------------------------------
#define NT_K (DMODEL / 32)   // 64 K-tiles

__device__ __forceinline__ void gemm_core(
    const f16* __restrict__ A, const f16* __restrict__ W,
    const float* __restrict__ bias, void* __restrict__ Cout,
    int mode, const float* __restrict__ sa, const float* __restrict__ sb)
{
    __shared__ f16 As[3][128 * 32];   // 8 KB per stage
    __shared__ f16 Bs[3][256 * 32];   // 16 KB per stage   (total 72 KB)

    const int tid = threadIdx.x;
    const int wid = tid >> 6;
    const int ln = tid & 15;
    const int quad = (tid & 63) >> 4;
    const int wm = (wid >> 2) * 64;    // wave row offset: 0 / 64
    const int wn = (wid & 3) * 64;     // wave col offset: 0 / 64 / 128 / 192
    const int bm = blockIdx.y * 128;
    const int bn = blockIdx.x * 256;
    const int K = DMODEL, N = DMODEL;

    f32x4 acc[4][4];
#pragma unroll
    for (int i = 0; i < 4; ++i)
#pragma unroll
        for (int j = 0; j < 4; ++j)
            acc[i][j] = (f32x4){0.f, 0.f, 0.f, 0.f};

    // staging addresses: lane -> (row = tid>>2, swizzled 16B chunk of the 64B row)
    const int sr = tid >> 2;                               // 0..127
    const int kcs = ((tid & 3) ^ ((tid >> 3) & 3)) * 8;    // pre-swizzled source chunk
    const f16* gA  = A + (size_t)(bm + sr) * K + kcs;
    const f16* gB0 = W + (size_t)(bn + sr) * K + kcs;
    const f16* gB1 = W + (size_t)(bn + 128 + sr) * K + kcs;
    // ds_read swizzle: same involution; row base is 16-aligned so (row>>1)&3 == (ln>>1)&3
    const int koff = (quad ^ ((ln >> 1) & 3)) * 8;

    // prologue: stage tiles 0 and 1 (3 loads per wave per tile: A, B-lo, B-hi)
    gl2lds16(gA,        &As[0][tid * 8]);
    gl2lds16(gB0,       &Bs[0][tid * 8]);
    gl2lds16(gB1,       &Bs[0][4096 + tid * 8]);
    gl2lds16(gA  + 32,  &As[1][tid * 8]);
    gl2lds16(gB0 + 32,  &Bs[1][tid * 8]);
    gl2lds16(gB1 + 32,  &Bs[1][4096 + tid * 8]);

    for (int t = 0; t < NT_K; ++t) {
        const f16* Ab = As[t % 3];
        const f16* Bb = Bs[t % 3];
        // tile-top sync: wait for THIS tile's 3 loads (oldest), leave the
        // next tile's 3 in flight. Never vmcnt(0) except at the last tile.
        if (t < NT_K - 1) asm volatile("s_waitcnt vmcnt(3)" ::: "memory");
        else              asm volatile("s_waitcnt vmcnt(0)" ::: "memory");
        __builtin_amdgcn_s_barrier();

        // ---- phase 1: frags (A rows 0-31 of wave, all B) + prefetch t+2 ----
        f16x8 af[2], bf[4];
#pragma unroll
        for (int i = 0; i < 2; ++i)
            af[i] = *(const f16x8*)&Ab[(wm + i * 16 + ln) * 32 + koff];
#pragma unroll
        for (int j = 0; j < 4; ++j)
            bf[j] = *(const f16x8*)&Bb[(wn + j * 16 + ln) * 32 + koff];
        if (t + 2 < NT_K) {
            const int b2 = (t + 2) % 3;
            const int k2 = (t + 2) * 32;
            gl2lds16(gA  + k2, &As[b2][tid * 8]);
            gl2lds16(gB0 + k2, &Bs[b2][tid * 8]);
        }
        __builtin_amdgcn_s_barrier();
        __builtin_amdgcn_s_setprio(1);
#pragma unroll
        for (int i = 0; i < 2; ++i)
#pragma unroll
            for (int j = 0; j < 4; ++j)
                acc[i][j] = __builtin_amdgcn_mfma_f32_16x16x32_f16(
                    af[i], bf[j], acc[i][j], 0, 0, 0);
        __builtin_amdgcn_s_setprio(0);
        __builtin_amdgcn_s_barrier();

        // ---- phase 2: frags (A rows 32-63 of wave) + rest of prefetch ----
#pragma unroll
        for (int i = 0; i < 2; ++i)
            af[i] = *(const f16x8*)&Ab[(wm + (2 + i) * 16 + ln) * 32 + koff];
        if (t + 2 < NT_K) {
            const int b2 = (t + 2) % 3;
            const int k2 = (t + 2) * 32;
            gl2lds16(gB1 + k2, &Bs[b2][4096 + tid * 8]);
        }
        __builtin_amdgcn_s_barrier();
        __builtin_amdgcn_s_setprio(1);
#pragma unroll
        for (int i = 0; i < 2; ++i)
#pragma unroll
            for (int j = 0; j < 4; ++j)
                acc[2 + i][j] = __builtin_amdgcn_mfma_f32_16x16x32_f16(
                    af[i], bf[j], acc[2 + i][j], 0, 0, 0);
        __builtin_amdgcn_s_setprio(0);
        // next tile's top vmcnt+barrier provides the closing sync
    }

    // epilogue: C/D layout col=lane&15, row=quad*4+reg
#pragma unroll
    for (int j = 0; j < 4; ++j) {
        const int n = bn + wn + j * 16 + ln;
        const float bn_ = bias[n];
        const int h = n >> 7;           // n / DK
        const int d = n & (DK - 1);
        float scq = 1.0f;
        if (mode == 3) scq = sa[h] / fmaxf(sb[h], 1.0f);
#pragma unroll
        for (int i = 0; i < 4; ++i) {
#pragma unroll
            for (int reg = 0; reg < 4; ++reg) {
                const int m = bm + wm + i * 16 + quad * 4 + reg;
                float v = acc[i][j][reg] + bn_;
                if (mode == 0) {
                    ((float*)Cout)[(size_t)m * N + n] = v;
                } else {
                    const int bb = m >> 11;          // / S_LEN
                    const int ss = m & (S_LEN - 1);
                    size_t idx;
                    if (mode == 2)
                        idx = (((size_t)(bb * NHEADS + h) * DK + d) * S_LEN + ss);
                    else
                        idx = (((size_t)(bb * NHEADS + h) * S_LEN + ss) * DK + d);
                    if (mode == 3) v *= scq;
                    ((f16*)Cout)[idx] = (f16)v;
                }
            }
        }
    }
}

__global__ __launch_bounds__(512, 2) void qkv_gemm(
    const f16* Aq, const f16* Ak, const f16* Av,
    const f16* Wq, const f16* Wk, const f16* Wv,
    const float* bq, const float* bk, const float* bv,
    f16* Oq, f16* Ok, f16* Ov, const float* sa, const float* sb)
{
    const int z = blockIdx.z;
    const f16* A = (z == 0) ? Aq : (z == 1) ? Ak : Av;
    const f16* W = (z == 0) ? Wq : (z == 1) ? Wk : Wv;
    const float* bias = (z == 0) ? bq : (z == 1) ? bk : bv;
    void* O = (z == 0) ? (void*)Oq : (z == 1) ? (void*)Ok : (void*)Ov;
    const int mode = (z == 0) ? 3 : (z == 1) ? 1 : 2;
    gemm_core(A, W, bias, O, mode, sa, sb);
}

__global__ __launch_bounds__(512, 2) void out_gemm(
    const f16* A, const f16* W, const float* bias, float* O)
{
    gemm_core(A, W, bias, O, 0, nullptr, nullptr);
}

// ---------------------------------------------------------------------------
// Flash attention v4 (fp16 MFMA, reduction-free softmax). UNCHANGED this
// round (next target: K/V/P LDS swizzle + counted-vmcnt pipeline).
// ---------------------------------------------------------------------------
__global__ __launch_bounds__(256, 2) void flash_v4(
    const f16* __restrict__ Qg, const f16* __restrict__ Kg,
    const f16* __restrict__ VTg, f16* __restrict__ AO)
{
    __shared__ f16 Ks[4 * 64 * 32];    // [kc][c][32]
    __shared__ f16 Vs[2 * 128 * 32];   // [cc][d][32]
    __shared__ f16 Ps[2 * 128 * 32];   // [cc][q][32]
    __shared__ float l_buf[2 * 128];   // [wc][q]

    const int tid = threadIdx.x;
    const int wid = tid >> 6;
    const int ln = tid & 15;
    const int quad = (tid & 63) >> 4;
    const int wq = wid & 1;
    const int wc = wid >> 1;
    const int bh = blockIdx.y;
    const int q0 = blockIdx.x * 128;

    // Q fragments to registers (wave's 64 q-rows, pre-scaled)
    f16x8 qf[4][4];
    const f16* Qbase = Qg + ((size_t)bh * S_LEN + q0 + wq * 64) * DK;
#pragma unroll
    for (int nt = 0; nt < 4; ++nt)
#pragma unroll
        for (int kc = 0; kc < 4; ++kc)
            qf[nt][kc] = *(const f16x8*)(Qbase + (size_t)(nt * 16 + ln) * DK
                                         + kc * 32 + quad * 8);

    f32x4 o[4][4];     // [mtq over q][ntd over d]
    float lp[4] = {0.f, 0.f, 0.f, 0.f};
#pragma unroll
    for (int i = 0; i < 4; ++i)
#pragma unroll
        for (int j = 0; j < 4; ++j)
            o[i][j] = (f32x4){0.f, 0.f, 0.f, 0.f};

    const f16* Kgb = Kg + (size_t)bh * S_LEN * DK;
    const f16* Vgb = VTg + (size_t)bh * DK * S_LEN;
    const int srow = tid >> 2;
    const int soff = (tid & 3) * 8;

    for (int kt = 0; kt < S_LEN / 64; ++kt) {
        __syncthreads();   // prior QK/PV done reading Ks/Vs/Ps
#pragma unroll
        for (int j = 0; j < 4; ++j)
            gl2lds16(Kgb + (size_t)(kt * 64 + srow) * DK + j * 32 + soff,
                     Ks + j * 2048 + tid * 8);
#pragma unroll
        for (int j = 0; j < 4; ++j)
            gl2lds16(Vgb + (size_t)(srow + (j & 1) * 64) * S_LEN
                         + kt * 64 + (j >> 1) * 32 + soff,
                     Vs + (j >> 1) * 4096 + (j & 1) * 2048 + tid * 8);
        __syncthreads();   // staging complete

        // S^T = K Q^T : wave quadrant [32 c][64 q], 32 MFMAs, 8 LDS reads
        f32x4 s[2][4];
#pragma unroll
        for (int mt = 0; mt < 2; ++mt)
#pragma unroll
            for (int nt = 0; nt < 4; ++nt)
                s[mt][nt] = (f32x4){0.f, 0.f, 0.f, 0.f};
#pragma unroll
        for (int kc = 0; kc < 4; ++kc) {
            f16x8 kf0 = *(const f16x8*)&Ks[kc * 2048 + (wc * 32 + ln) * 32 + quad * 8];
            f16x8 kf1 = *(const f16x8*)&Ks[kc * 2048 + (wc * 32 + 16 + ln) * 32 + quad * 8];
#pragma unroll
            for (int nt = 0; nt < 4; ++nt) {
                s[0][nt] = __builtin_amdgcn_mfma_f32_16x16x32_f16(kf0, qf[nt][kc], s[0][nt], 0, 0, 0);
                s[1][nt] = __builtin_amdgcn_mfma_f32_16x16x32_f16(kf1, qf[nt][kc], s[1][nt], 0, 0, 0);
            }
        }

        // exp (no max-sub), in-lane l partials, vectorized P write
#pragma unroll
        for (int mt = 0; mt < 2; ++mt) {
#pragma unroll
            for (int nt = 0; nt < 4; ++nt) {
                const float p0 = __expf(s[mt][nt][0]);
                const float p1 = __expf(s[mt][nt][1]);
                const float p2 = __expf(s[mt][nt][2]);
                const float p3 = __expf(s[mt][nt][3]);
                lp[nt] += (p0 + p1) + (p2 + p3);
                f16x4 pk;
                pk[0] = (f16)p0; pk[1] = (f16)p1; pk[2] = (f16)p2; pk[3] = (f16)p3;
                *(f16x4*)&Ps[wc * 4096 + (wq * 64 + nt * 16 + ln) * 32
                             + mt * 16 + quad * 4] = pk;
            }
        }
        __syncthreads();   // P visible to all waves

        // O += P V : wave quadrant [64 q][64 d], 32 MFMAs, 16 LDS reads
#pragma unroll
        for (int cc = 0; cc < 2; ++cc) {
            f16x8 pf[4];
#pragma unroll
            for (int mtq = 0; mtq < 4; ++mtq)
                pf[mtq] = *(const f16x8*)&Ps[cc * 4096 + (wq * 64 + mtq * 16 + ln) * 32 + quad * 8];
#pragma unroll
            for (int ntd = 0; ntd < 4; ++ntd) {
                f16x8 vf = *(const f16x8*)&Vs[cc * 4096 + (wc * 64 + ntd * 16 + ln) * 32 + quad * 8];
#pragma unroll
                for (int mtq = 0; mtq < 4; ++mtq)
                    o[mtq][ntd] = __builtin_amdgcn_mfma_f32_16x16x32_f16(
                        pf[mtq], vf, o[mtq][ntd], 0, 0, 0);
            }
        }
    }

    // finalize l: reduce over quads (c-spread), publish per (wc, q)
#pragma unroll
    for (int nt = 0; nt < 4; ++nt) {
        float v = lp[nt];
        v += __shfl_xor(v, 16, 64);
        v += __shfl_xor(v, 32, 64);
        lp[nt] = v;
    }
    if (quad == 0) {
#pragma unroll
        for (int nt = 0; nt < 4; ++nt)
            l_buf[wc * 128 + wq * 64 + nt * 16 + ln] = lp[nt];
    }
    __syncthreads();

    // epilogue: AO[b][s][h*DK + d] = o / l
    const int b = bh >> 4;
    const int h = bh & (NHEADS - 1);
#pragma unroll
    for (int mtq = 0; mtq < 4; ++mtq) {
#pragma unroll
        for (int reg = 0; reg < 4; ++reg) {
            const int ql = wq * 64 + mtq * 16 + quad * 4 + reg;
            const float inv = 1.0f / (l_buf[ql] + l_buf[128 + ql]);
            f16* dst = AO + ((size_t)b * S_LEN + q0 + ql) * DMODEL + h * DK + wc * 64;
#pragma unroll
            for (int ntd = 0; ntd < 4; ++ntd)
                dst[ntd * 16 + ln] = (f16)(o[mtq][ntd][reg] * inv);
        }
    }
}

// ---------------------------------------------------------------------------
extern "C" void kernel_launch(void* const* d_in, const int* in_sizes, int n_in,
                              void* d_out, int out_size, void* d_ws, size_t ws_size,
                              hipStream_t stream)
{
    (void)in_sizes; (void)n_in; (void)out_size; (void)ws_size;
    const float* query = (const float*)d_in[0];
    const float* key_  = (const float*)d_in[1];
    const float* value = (const float*)d_in[2];
    const float* w_q = (const float*)d_in[3];
    const float* b_q = (const float*)d_in[4];
    const float* w_k = (const float*)d_in[5];
    const float* b_k = (const float*)d_in[6];
    const float* w_v = (const float*)d_in[7];
    const float* b_v = (const float*)d_in[8];
    const float* w_o = (const float*)d_in[9];
    const float* b_o = (const float*)d_in[10];
    const float* s_alpha = (const float*)d_in[11];
    const float* s_beta  = (const float*)d_in[12];
    float* out = (float*)d_out;

    const size_t T = (size_t)MROWS * DMODEL;    // 8,388,608
    const size_t Wn = (size_t)DMODEL * DMODEL;  // 4,194,304
    f16* base = (f16*)d_ws;
    f16* c_q = base;              // later reused as Kh
    f16* c_k = base + T;          // later reused as VT
    f16* c_v = base + 2 * T;      // later reused as AOh
    f16* Qh  = base + 3 * T;
    f16* wq16 = base + 4 * T;
    f16* wk16 = wq16 + Wn;
    f16* wv16 = wk16 + Wn;
    f16* wo16 = wv16 + Wn;
    f16* Kh  = c_q;
    f16* VT  = c_k;
    f16* AOh = c_v;

    cvt_all<<<dim3(CVT_BLOCKS), dim3(256), 0, stream>>>(
        query, key_, value, w_q, w_k, w_v, w_o,
        c_q, c_k, c_v, wq16, wk16, wv16, wo16);

    dim3 qkv_grid(DMODEL / 256, MROWS / 128, 3);  // (8, 32, 3) = 768 blocks
    qkv_gemm<<<qkv_grid, dim3(512), 0, stream>>>(c_q, c_k, c_v, wq16, wk16, wv16,
                                                 b_q, b_k, b_v, Qh, Kh, VT,
                                                 s_alpha, s_beta);

    dim3 flash_grid(S_LEN / 128, 2 * NHEADS);     // (16, 32)
    flash_v4<<<flash_grid, dim3(256), 0, stream>>>(Qh, Kh, VT, AOh);

    dim3 out_grid(DMODEL / 256, MROWS / 128);     // (8, 32) = 256 blocks
    out_gemm<<<out_grid, dim3(512), 0, stream>>>(AOh, wo16, b_o, out);
}

// Round 4
// 484.342 us; speedup vs baseline: 1.0287x; 1.0287x over previous
//
#include <hip/hip_runtime.h>
#include <cstdint>

// FracAttention: B=2, S=2048, D_MODEL=2048, H=16, DK=128
// Round 4 = round-3 source resubmitted verbatim: round-3 bench was an
// infrastructure failure (container acquisition), not a kernel failure.
#define S_LEN   2048
#define DMODEL  2048
#define NHEADS  16
#define DK      128
#define MROWS   4096   // B*S

typedef _Float16 f16;
using f16x8 = __attribute__((ext_vector_type(8))) _Float16;
using f16x4 = __attribute__((ext_vector_type(4))) _Float16;
using f32x4 = __attribute__((ext_vector_type(4))) float;

typedef const __attribute__((address_space(1))) unsigned int gu32;
typedef __attribute__((address_space(3))) unsigned int lu32;

__device__ __forceinline__ void gl2lds16(const void* g, void* l) {
    // async global->LDS, 16 B per lane; LDS dest = wave-uniform base + lane*16
    __builtin_amdgcn_global_load_lds((gu32*)g, (lu32*)l, 16, 0, 0);
}

// ---------------------------------------------------------------------------
// fp32 -> fp16 convert, all 7 tensors in one dispatch (round-0 form,
// measured 60.5us).
// ---------------------------------------------------------------------------
__global__ __launch_bounds__(256) void cvt_all(
    const float* __restrict__ q, const float* __restrict__ k,
    const float* __restrict__ v, const float* __restrict__ wq,
    const float* __restrict__ wk, const float* __restrict__ wv,
    const float* __restrict__ wo,
    f16* cq, f16* ck, f16* cv, f16* cwq, f16* cwk, f16* cwv, f16* cwo)
{
    const int b = blockIdx.x;
    const float* src; f16* dst; int base;
    if      (b <  8192) { src = q;  dst = cq;  base = b; }
    else if (b < 16384) { src = k;  dst = ck;  base = b - 8192; }
    else if (b < 24576) { src = v;  dst = cv;  base = b - 16384; }
    else if (b < 28672) { src = wq; dst = cwq; base = b - 24576; }
    else if (b < 32768) { src = wk; dst = cwk; base = b - 28672; }
    else if (b < 36864) { src = wv; dst = cwv; base = b - 32768; }
    else                { src = wo; dst = cwo; base = b - 36864; }
    const int i = base * 256 + threadIdx.x;
    float4 x = ((const float4*)src)[i];
    f16x4 o; o[0] = (f16)x.x; o[1] = (f16)x.y; o[2] = (f16)x.z; o[3] = (f16)x.w;
    ((f16x4*)dst)[i] = o;
}

// ---------------------------------------------------------------------------
// fp16 MFMA GEMM core v3: C[M][N] = A[M][K] @ W[N][K]^T + bias
// BM=256 x BN (256 or 128), BK=32, 512 threads = 8 waves (2 rows x 4 cols),
// per-wave output 128 x (BN/4): 8 x NJ fragments of 16x16 -> 0.375 KB of
// ds_read per MFMA (MFMA-dominant; a 64x64 wave tile is LDS-read-bound).
// Quad-buffered LDS, stage 3 K-tiles ahead via global_load_lds; ONE barrier
// per K-tile with a counted s_waitcnt (never 0 until the tail) so loads span
// barriers (T3+T4). sched_barrier(0) right after s_barrier: raw s_barrier is
// NOT a compiler fence -- without it hipcc may hoist the ds_reads above the
// barrier (reads race other waves' in-flight global_load_lds writes).
// Two 16-MFMA phases per tile, each pinned by lgkmcnt(0)+sched_barrier(0)
// and wrapped in setprio (T5). T2 XOR swizzle (verified: conflicts -> 0).
// NOTE on aliasing (round-2 post-mortem): outputs of this kernel must NOT
// alias inputs of the SAME launch -- co-resident z-slices race (epilogue
// writes vs other slices' A-reads). Kh/VT now live in d_out.
// mode 0: fp32 out [M][N]
// mode 1: f16 out head-permuted [B,H,S,DK]              (K)
// mode 2: f16 out head-permuted + transposed [B,H,DK,S] (V -> VT)
// mode 3: f16 out head-permuted, scaled by sa[h]/max(sb[h],1) (Q)
// ---------------------------------------------------------------------------
#define NT_K (DMODEL / 32)   // 64 K-tiles

template<int BN>
__device__ __forceinline__ void gemm_core2(
    const f16* __restrict__ A, const f16* __restrict__ W,
    const float* __restrict__ bias, void* __restrict__ Cout,
    int mode, const float* __restrict__ sa, const float* __restrict__ sb)
{
    constexpr int NJ = BN / 64;            // frag-cols per wave: 4 or 2
    __shared__ f16 As[4][256 * 32];        // 64 KB
    __shared__ f16 Bs[4][BN * 32];         // 64 KB (BN=256) / 32 KB (BN=128)

    const int tid  = threadIdx.x;
    const int wid  = tid >> 6;
    const int ln   = tid & 15;
    const int quad = (tid & 63) >> 4;
    const int wm   = (wid >> 2) * 128;     // wave row: 0 / 128
    const int wn   = (wid & 3) * (16 * NJ);// wave col: stride 64 (or 32)
    const int bm   = blockIdx.y * 256;
    const int bn   = blockIdx.x * BN;
    const int K = DMODEL, N = DMODEL;

    f32x4 acc[8][NJ];
#pragma unroll
    for (int i = 0; i < 8; ++i)
#pragma unroll
        for (int j = 0; j < NJ; ++j)
            acc[i][j] = (f32x4){0.f, 0.f, 0.f, 0.f};

    // staging: thread -> row tid>>2 (and +128), 16B chunk (tid&3) pre-swizzled
    const int sr  = tid >> 2;
    const int kcs = ((tid & 3) ^ ((tid >> 3) & 3)) * 8;
    const f16* gA0 = A + (size_t)(bm + sr) * K + kcs;
    const f16* gA1 = A + (size_t)(bm + 128 + sr) * K + kcs;
    const f16* gB0 = W + (size_t)(bn + sr) * K + kcs;
    const f16* gB1 = W + (size_t)(bn + 128 + sr) * K + kcs;   // BN=256 only
    // ds_read swizzle: same involution; frag rows are 16-aligned + ln
    const int koff = (quad ^ ((ln >> 1) & 3)) * 8;

#define STAGE_A(t_) do { const int b_ = (t_) & 3; const int k_ = (t_) * 32; \
        gl2lds16(gA0 + k_, &As[b_][tid * 8]);                               \
        gl2lds16(gA1 + k_, &As[b_][4096 + tid * 8]); } while (0)
#define STAGE_B(t_) do { const int b_ = (t_) & 3; const int k_ = (t_) * 32; \
        gl2lds16(gB0 + k_, &Bs[b_][tid * 8]);                               \
        if (BN == 256) gl2lds16(gB1 + k_, &Bs[b_][4096 + tid * 8]); } while (0)

    // prologue: stage tiles 0,1,2 (issue order A-then-B per tile, preserved)
    STAGE_A(0); STAGE_B(0);
    STAGE_A(1); STAGE_B(1);
    STAGE_A(2); STAGE_B(2);

    for (int t = 0; t < NT_K; ++t) {
        const f16* Ab = As[t & 3];
        const f16* Bb = Bs[t & 3];
        // counted wait: retire exactly tile t's loads (oldest LPT), keep the
        // 2 newer tiles' loads in flight. LPT = 4 (BN=256) or 3 (BN=128).
        if (BN == 256) {
            if (t < NT_K - 2)       asm volatile("s_waitcnt vmcnt(8)" ::: "memory");
            else if (t == NT_K - 2) asm volatile("s_waitcnt vmcnt(4)" ::: "memory");
            else                    asm volatile("s_waitcnt vmcnt(0)" ::: "memory");
        } else {
            if (t < NT_K - 2)       asm volatile("s_waitcnt vmcnt(6)" ::: "memory");
            else if (t == NT_K - 2) asm volatile("s_waitcnt vmcnt(3)" ::: "memory");
            else                    asm volatile("s_waitcnt vmcnt(0)" ::: "memory");
        }
        __builtin_amdgcn_s_barrier();        // buf[t&3] globally ready
        __builtin_amdgcn_sched_barrier(0);   // pin: nothing hoists above barrier

        // ---- phase 1: frag rows 0-3 x all cols; prefetch A of t+3 ----
        f16x8 af[4], bf[NJ];
#pragma unroll
        for (int i = 0; i < 4; ++i)
            af[i] = *(const f16x8*)&Ab[(wm + i * 16 + ln) * 32 + koff];
#pragma unroll
        for (int j = 0; j < NJ; ++j)
            bf[j] = *(const f16x8*)&Bb[(wn + j * 16 + ln) * 32 + koff];
        if (t + 3 < NT_K) STAGE_A(t + 3);
        asm volatile("s_waitcnt lgkmcnt(0)" ::: "memory");
        __builtin_amdgcn_sched_barrier(0);
        __builtin_amdgcn_s_setprio(1);
#pragma unroll
        for (int i = 0; i < 4; ++i)
#pragma unroll
            for (int j = 0; j < NJ; ++j)
                acc[i][j] = __builtin_amdgcn_mfma_f32_16x16x32_f16(
                    af[i], bf[j], acc[i][j], 0, 0, 0);
        __builtin_amdgcn_s_setprio(0);

        // ---- phase 2: frag rows 4-7; prefetch B of t+3 ----
#pragma unroll
        for (int i = 0; i < 4; ++i)
            af[i] = *(const f16x8*)&Ab[(wm + (4 + i) * 16 + ln) * 32 + koff];
        if (t + 3 < NT_K) STAGE_B(t + 3);
        asm volatile("s_waitcnt lgkmcnt(0)" ::: "memory");
        __builtin_amdgcn_sched_barrier(0);
        __builtin_amdgcn_s_setprio(1);
#pragma unroll
        for (int i = 0; i < 4; ++i)
#pragma unroll
            for (int j = 0; j < NJ; ++j)
                acc[4 + i][j] = __builtin_amdgcn_mfma_f32_16x16x32_f16(
                    af[i], bf[j], acc[4 + i][j], 0, 0, 0);
        __builtin_amdgcn_s_setprio(0);
        // next tile's vmcnt+barrier closes the tile
    }
#undef STAGE_A
#undef STAGE_B

    // epilogue: C/D layout col=lane&15, row=quad*4+reg
#pragma unroll
    for (int j = 0; j < NJ; ++j) {
        const int n = bn + wn + j * 16 + ln;
        const float bn_ = bias[n];
        const int h = n >> 7;           // n / DK
        const int d = n & (DK - 1);
        float scq = 1.0f;
        if (mode == 3) scq = sa[h] / fmaxf(sb[h], 1.0f);
#pragma unroll
        for (int i = 0; i < 8; ++i) {
#pragma unroll
            for (int reg = 0; reg < 4; ++reg) {
                const int m = bm + wm + i * 16 + quad * 4 + reg;
                float v = acc[i][j][reg] + bn_;
                if (mode == 0) {
                    ((float*)Cout)[(size_t)m * N + n] = v;
                } else {
                    const int bb = m >> 11;          // / S_LEN
                    const int ss = m & (S_LEN - 1);
                    size_t idx;
                    if (mode == 2)
                        idx = (((size_t)(bb * NHEADS + h) * DK + d) * S_LEN + ss);
                    else
                        idx = (((size_t)(bb * NHEADS + h) * S_LEN + ss) * DK + d);
                    if (mode == 3) v *= scq;
                    ((f16*)Cout)[idx] = (f16)v;
                }
            }
        }
    }
}

__global__ __launch_bounds__(512, 2) void qkv_gemm(
    const f16* Aq, const f16* Ak, const f16* Av,
    const f16* Wq, const f16* Wk, const f16* Wv,
    const float* bq, const float* bk, const float* bv,
    f16* Oq, f16* Ok, f16* Ov, const float* sa, const float* sb)
{
    const int z = blockIdx.z;
    const f16* A = (z == 0) ? Aq : (z == 1) ? Ak : Av;
    const f16* W = (z == 0) ? Wq : (z == 1) ? Wk : Wv;
    const float* bias = (z == 0) ? bq : (z == 1) ? bk : bv;
    void* O = (z == 0) ? (void*)Oq : (z == 1) ? (void*)Ok : (void*)Ov;
    const int mode = (z == 0) ? 3 : (z == 1) ? 1 : 2;
    gemm_core2<256>(A, W, bias, O, mode, sa, sb);
}

__global__ __launch_bounds__(512, 2) void out_gemm(
    const f16* A, const f16* W, const float* bias, float* O)
{
    gemm_core2<128>(A, W, bias, O, 0, nullptr, nullptr);
}

// ---------------------------------------------------------------------------
// Flash attention v5: v4 + T2 XOR swizzle on Ks/Vs (pre-swizzled global
// source chunk, swizzled ds_read) and on Ps (swizzled ds_write + ds_read),
// + setprio around both MFMA clusters. Uses __syncthreads (full fence) so no
// barrier-hoist hazard here.
// ---------------------------------------------------------------------------
__global__ __launch_bounds__(256, 2) void flash_v4(
    const f16* __restrict__ Qg, const f16* __restrict__ Kg,
    const f16* __restrict__ VTg, f16* __restrict__ AO)
{
    __shared__ f16 Ks[4 * 64 * 32];    // [kc][c][32]
    __shared__ f16 Vs[2 * 128 * 32];   // [cc][d][32]
    __shared__ f16 Ps[2 * 128 * 32];   // [cc][q][32]
    __shared__ float l_buf[2 * 128];   // [wc][q]

    const int tid = threadIdx.x;
    const int wid = tid >> 6;
    const int ln = tid & 15;
    const int quad = (tid & 63) >> 4;
    const int wq = wid & 1;
    const int wc = wid >> 1;
    const int bh = blockIdx.y;
    const int q0 = blockIdx.x * 128;

    // T2 swizzle keys: read rows are (16-aligned + ln) -> key (ln>>1)&3;
    // staging rows are tid>>2 -> key (tid>>3)&3.
    const int koff = (quad ^ ((ln >> 1) & 3)) * 8;                 // read, b128
    const int soff_sw = ((tid & 3) ^ ((tid >> 3) & 3)) * 8;        // staging src

    // Q fragments to registers (wave's 64 q-rows, pre-scaled)
    f16x8 qf[4][4];
    const f16* Qbase = Qg + ((size_t)bh * S_LEN + q0 + wq * 64) * DK;
#pragma unroll
    for (int nt = 0; nt < 4; ++nt)
#pragma unroll
        for (int kc = 0; kc < 4; ++kc)
            qf[nt][kc] = *(const f16x8*)(Qbase + (size_t)(nt * 16 + ln) * DK
                                         + kc * 32 + quad * 8);

    f32x4 o[4][4];     // [mtq over q][ntd over d]
    float lp[4] = {0.f, 0.f, 0.f, 0.f};
#pragma unroll
    for (int i = 0; i < 4; ++i)
#pragma unroll
        for (int j = 0; j < 4; ++j)
            o[i][j] = (f32x4){0.f, 0.f, 0.f, 0.f};

    const f16* Kgb = Kg + (size_t)bh * S_LEN * DK;
    const f16* Vgb = VTg + (size_t)bh * DK * S_LEN;
    const int srow = tid >> 2;

    for (int kt = 0; kt < S_LEN / 64; ++kt) {
        __syncthreads();   // prior QK/PV done reading Ks/Vs/Ps
#pragma unroll
        for (int j = 0; j < 4; ++j)
            gl2lds16(Kgb + (size_t)(kt * 64 + srow) * DK + j * 32 + soff_sw,
                     Ks + j * 2048 + tid * 8);
#pragma unroll
        for (int j = 0; j < 4; ++j)
            gl2lds16(Vgb + (size_t)(srow + (j & 1) * 64) * S_LEN
                         + kt * 64 + (j >> 1) * 32 + soff_sw,
                     Vs + (j >> 1) * 4096 + (j & 1) * 2048 + tid * 8);
        __syncthreads();   // staging complete

        // S^T = K Q^T : wave quadrant [32 c][64 q], 32 MFMAs, 8 LDS reads
        f32x4 s[2][4];
#pragma unroll
        for (int mt = 0; mt < 2; ++mt)
#pragma unroll
            for (int nt = 0; nt < 4; ++nt)
                s[mt][nt] = (f32x4){0.f, 0.f, 0.f, 0.f};
        __builtin_amdgcn_s_setprio(1);
#pragma unroll
        for (int kc = 0; kc < 4; ++kc) {
            f16x8 kf0 = *(const f16x8*)&Ks[kc * 2048 + (wc * 32 + ln) * 32 + koff];
            f16x8 kf1 = *(const f16x8*)&Ks[kc * 2048 + (wc * 32 + 16 + ln) * 32 + koff];
#pragma unroll
            for (int nt = 0; nt < 4; ++nt) {
                s[0][nt] = __builtin_amdgcn_mfma_f32_16x16x32_f16(kf0, qf[nt][kc], s[0][nt], 0, 0, 0);
                s[1][nt] = __builtin_amdgcn_mfma_f32_16x16x32_f16(kf1, qf[nt][kc], s[1][nt], 0, 0, 0);
            }
        }
        __builtin_amdgcn_s_setprio(0);

        // exp (no max-sub), in-lane l partials, swizzled vectorized P write
#pragma unroll
        for (int mt = 0; mt < 2; ++mt) {
#pragma unroll
            for (int nt = 0; nt < 4; ++nt) {
                const float p0 = __expf(s[mt][nt][0]);
                const float p1 = __expf(s[mt][nt][1]);
                const float p2 = __expf(s[mt][nt][2]);
                const float p3 = __expf(s[mt][nt][3]);
                lp[nt] += (p0 + p1) + (p2 + p3);
                f16x4 pk;
                pk[0] = (f16)p0; pk[1] = (f16)p1; pk[2] = (f16)p2; pk[3] = (f16)p3;
                // logical 16B chunk = mt*2 + (quad>>1); swizzle by (ln>>1)&3
                const int pchunk = ((mt * 2 + (quad >> 1)) ^ ((ln >> 1) & 3)) * 8
                                   + (quad & 1) * 4;
                *(f16x4*)&Ps[wc * 4096 + (wq * 64 + nt * 16 + ln) * 32 + pchunk] = pk;
            }
        }
        __syncthreads();   // P visible to all waves

        // O += P V : wave quadrant [64 q][64 d], 32 MFMAs, 16 LDS reads
        __builtin_amdgcn_s_setprio(1);
#pragma unroll
        for (int cc = 0; cc < 2; ++cc) {
            f16x8 pf[4];
#pragma unroll
            for (int mtq = 0; mtq < 4; ++mtq)
                pf[mtq] = *(const f16x8*)&Ps[cc * 4096 + (wq * 64 + mtq * 16 + ln) * 32 + koff];
#pragma unroll
            for (int ntd = 0; ntd < 4; ++ntd) {
                f16x8 vf = *(const f16x8*)&Vs[cc * 4096 + (wc * 64 + ntd * 16 + ln) * 32 + koff];
#pragma unroll
                for (int mtq = 0; mtq < 4; ++mtq)
                    o[mtq][ntd] = __builtin_amdgcn_mfma_f32_16x16x32_f16(
                        pf[mtq], vf, o[mtq][ntd], 0, 0, 0);
            }
        }
        __builtin_amdgcn_s_setprio(0);
    }

    // finalize l: reduce over quads (c-spread), publish per (wc, q)
#pragma unroll
    for (int nt = 0; nt < 4; ++nt) {
        float v = lp[nt];
        v += __shfl_xor(v, 16, 64);
        v += __shfl_xor(v, 32, 64);
        lp[nt] = v;
    }
    if (quad == 0) {
#pragma unroll
        for (int nt = 0; nt < 4; ++nt)
            l_buf[wc * 128 + wq * 64 + nt * 16 + ln] = lp[nt];
    }
    __syncthreads();

    // epilogue: AO[b][s][h*DK + d] = o / l
    const int b = bh >> 4;
    const int h = bh & (NHEADS - 1);
#pragma unroll
    for (int mtq = 0; mtq < 4; ++mtq) {
#pragma unroll
        for (int reg = 0; reg < 4; ++reg) {
            const int ql = wq * 64 + mtq * 16 + quad * 4 + reg;
            const float inv = 1.0f / (l_buf[ql] + l_buf[128 + ql]);
            f16* dst = AO + ((size_t)b * S_LEN + q0 + ql) * DMODEL + h * DK + wc * 64;
#pragma unroll
            for (int ntd = 0; ntd < 4; ++ntd)
                dst[ntd * 16 + ln] = (f16)(o[mtq][ntd][reg] * inv);
        }
    }
}

// ---------------------------------------------------------------------------
// Buffer plan (race-free):
//   ws: c_q, c_k, c_v (cvt outputs; qkv inputs), Qh, 4x weights.
//   d_out (32MB) holds Kh (16MB) + VT (16MB) between qkv_gemm and flash --
//   d_out is dead until out_gemm, which runs after flash and fully
//   overwrites it. AOh aliases c_v (c_v's last reader is qkv; flash is a
//   later launch). NO output of any launch aliases an input of the SAME
//   launch (round-2 tripwire root cause).
// ---------------------------------------------------------------------------
extern "C" void kernel_launch(void* const* d_in, const int* in_sizes, int n_in,
                              void* d_out, int out_size, void* d_ws, size_t ws_size,
                              hipStream_t stream)
{
    (void)in_sizes; (void)n_in; (void)out_size; (void)ws_size;
    const float* query = (const float*)d_in[0];
    const float* key_  = (const float*)d_in[1];
    const float* value = (const float*)d_in[2];
    const float* w_q = (const float*)d_in[3];
    const float* b_q = (const float*)d_in[4];
    const float* w_k = (const float*)d_in[5];
    const float* b_k = (const float*)d_in[6];
    const float* w_v = (const float*)d_in[7];
    const float* b_v = (const float*)d_in[8];
    const float* w_o = (const float*)d_in[9];
    const float* b_o = (const float*)d_in[10];
    const float* s_alpha = (const float*)d_in[11];
    const float* s_beta  = (const float*)d_in[12];
    float* out = (float*)d_out;

    const size_t T = (size_t)MROWS * DMODEL;    // 8,388,608
    const size_t Wn = (size_t)DMODEL * DMODEL;  // 4,194,304
    f16* base = (f16*)d_ws;
    f16* c_q = base;
    f16* c_k = base + T;
    f16* c_v = base + 2 * T;      // later reused as AOh (cross-launch, safe)
    f16* Qh  = base + 3 * T;
    f16* wq16 = base + 4 * T;
    f16* wk16 = wq16 + Wn;
    f16* wv16 = wk16 + Wn;
    f16* wo16 = wv16 + Wn;
    f16* Kh  = (f16*)d_out;       // 16MB: first half of d_out
    f16* VT  = Kh + T;            // 16MB: second half of d_out
    f16* AOh = c_v;

    cvt_all<<<dim3(40960), dim3(256), 0, stream>>>(
        query, key_, value, w_q, w_k, w_v, w_o,
        c_q, c_k, c_v, wq16, wk16, wv16, wo16);

    dim3 qkv_grid(DMODEL / 256, MROWS / 256, 3);  // (8, 16, 3) = 384 blocks
    qkv_gemm<<<qkv_grid, dim3(512), 0, stream>>>(c_q, c_k, c_v, wq16, wk16, wv16,
                                                 b_q, b_k, b_v, Qh, Kh, VT,
                                                 s_alpha, s_beta);

    dim3 flash_grid(S_LEN / 128, 2 * NHEADS);     // (16, 32)
    flash_v4<<<flash_grid, dim3(256), 0, stream>>>(Qh, Kh, VT, AOh);

    dim3 out_grid(DMODEL / 128, MROWS / 256);     // (16, 16) = 256 blocks
    out_gemm<<<out_grid, dim3(512), 0, stream>>>(AOh, wo16, b_o, out);
}